// Round 14
// baseline (357.620 us; speedup 1.0000x reference)
//
#include <hip/hip_runtime.h>
#include <math.h>

// ---------------------------------------------------------------------------
// HimNet multimode v17. B=8,N=1000,CIN=16,H=64,D=16,K=3,XIN=80,K*XIN=240,2H=128
//
// v17 = v16 + gate meta rebuilt as meta3g: 128 rows x 64 cols per block,
// 512 threads (8 waves, 4x2). Each 32KB B-tile stage feeds 2x the MFMAs;
// total gate B traffic halves (378 x 512KB = 194MB vs 408MB). A-prologue
// staged in 2 phases through the same 32KB buffer; per-wave afr[2][8]
// unchanged (proven AGPR-resident). Plain __syncthreads (v6 semantics).
// update = split-d meta3u + epi_u (v16). cheb_v6 + prep_aux (v15/v14).
// Closed lines: meta3 intra-block pipelining (v5/v8/v9/v10/v12/v13);
// gate split-d (1500 blocks > 1024 residency slots -> 2 rounds, worse).
// ---------------------------------------------------------------------------

typedef __attribute__((ext_vector_type(8))) short s16x8;
typedef __attribute__((ext_vector_type(4))) float f32x4;
typedef unsigned short u16;
typedef unsigned int u32;
typedef unsigned long long u64;

__device__ __forceinline__ u32 f2bf(float f) {
  union { float f; u32 u; } v; v.f = f;
  return (v.u + 0x7FFFu + ((v.u >> 16) & 1u)) >> 16;  // RNE
}
__device__ __forceinline__ float bf2f(u16 h) {
  union { u32 u; float f; } v; v.u = (u32)h << 16; return v.f;
}
__device__ __forceinline__ u64 pk4(float a, float b, float c, float d) {
  return (u64)f2bf(a) | ((u64)f2bf(b) << 16) | ((u64)f2bf(c) << 32) |
         ((u64)f2bf(d) << 48);
}
__device__ __forceinline__ void glds16(const u16* g, u16* l) {
  __builtin_amdgcn_global_load_lds(
      (const __attribute__((address_space(1))) void*)g,
      (__attribute__((address_space(3))) void*)l, 16, 0, 0);
}

// ---------------------------------------------------------------------------
// prep_aux: prep (4 elems/thread) + aux (1 elem/thread) in one launch.
// ---------------------------------------------------------------------------
#define E0 3145728
#define E1 1966080
#define E2 1920000
#define E3 384000
#define E4 384000
#define E5 384000
#define E6 119808
// prep total = 8303616 elems = 2075904 threads; aux total = 1362432 threads
// grid = 8109 + 5322 = 13431 blocks of 256

struct PrepAuxArgs {
  const float* x[3]; const float* st[3]; const float* S[3];
  u16 *S16, *Xt, *Ag, *AgU, *T1t, *ZSt, *SZ1t;
  const float *e0, *e1, *e2, *me, *Bg, *Bu, *Wg, *Wu;
  float *BiG, *BiU; u16 *BtG, *BtU;
};

__global__ void prep_aux(PrepAuxArgs P) {
  long tid = (long)blockIdx.x * 256 + threadIdx.x;
  if (tid < 2075904) {        // ---- prep path: 4 elems ----
    long idx = tid * 4;
    if (idx < E0) {  // S16 incl pads: 4 consecutive k, same n
      int m = (int)(idx >> 20); int rem = (int)(idx & 1048575);
      int n = rem >> 10, k = rem & 1023;
      u64 pv = 0;
      if (n < 1000 && k < 1000) {
        f32x4 v = *(const f32x4*)&P.S[m][n * 1000 + k];
        pv = pk4(v[0], v[1], v[2], v[3]);
      }
      *(u64*)&P.S16[(size_t)m * 1048576 + rem] = pv; return;
    }
    idx -= E0;
    if (idx < E1) {  // Xt: 4 consecutive nn, same col
      int m = (int)(idx / 655360); int rem = (int)(idx % 655360);
      int col = rem >> 10, nn = rem & 1023;
      int b = col / 80, c = col % 80;
      u64 pv = 0;
      if (nn < 1000) {
        float f[4];
#pragma unroll
        for (int j = 0; j < 4; ++j)
          f[j] = (c < 16) ? P.x[m][(b * 1000 + nn + j) * 16 + c]
                          : P.st[m][(b * 1000 + nn + j) * 64 + c - 16];
        pv = pk4(f[0], f[1], f[2], f[3]);
      }
      *(u64*)&P.Xt[(size_t)m * 655360 + rem] = pv; return;
    }
    idx -= E1;
    if (idx < E2) {  // Ag kc0: 4 consecutive c, same r
      int m = (int)(idx / 640000); int rem = (int)(idx % 640000);
      int r = rem / 80, c = rem % 80;
      int n = r >> 3, b = r & 7;
      f32x4 v = (c < 16) ? *(const f32x4*)&P.x[m][(b * 1000 + n) * 16 + c]
                         : *(const f32x4*)&P.st[m][(b * 1000 + n) * 64 + c - 16];
      *(u64*)&P.Ag[(size_t)m * 2048000 + (size_t)r * 256 + c] =
          pk4(v[0], v[1], v[2], v[3]);
      return;
    }
    idx -= E2;
    if (idx < E3) {  // Ag K-pad 240..255
      int m = (int)(idx / 128000); int rem = (int)(idx % 128000);
      int r = rem / 16, c = 240 + rem % 16;
      *(u64*)&P.Ag[(size_t)m * 2048000 + (size_t)r * 256 + c] = 0; return;
    }
    idx -= E3;
    if (idx < E4) {  // AgU kc0 x-part (cols 0..15)
      int m = (int)(idx / 128000); int rem = (int)(idx % 128000);
      int r = rem / 16, c = rem % 16;
      int n = r >> 3, b = r & 7;
      f32x4 v = *(const f32x4*)&P.x[m][(b * 1000 + n) * 16 + c];
      *(u64*)&P.AgU[(size_t)m * 2048000 + (size_t)r * 256 + c] =
          pk4(v[0], v[1], v[2], v[3]);
      return;
    }
    idx -= E4;
    if (idx < E5) {  // AgU K-pad
      int m = (int)(idx / 128000); int rem = (int)(idx % 128000);
      int r = rem / 16, c = 240 + rem % 16;
      *(u64*)&P.AgU[(size_t)m * 2048000 + (size_t)r * 256 + c] = 0; return;
    }
    idx -= E5;
    if (idx < E6) {  // n-pad rows (k=1000..1023) of T1t/ZSt/SZ1t
      int m = (int)(idx / 39936); int rem = (int)(idx % 39936);
      if (rem < 15360) { int col = rem / 24, j = rem % 24;
        *(u64*)&P.T1t[(size_t)m * 655360 + col * 1024 + 1000 + j] = 0; }
      else if (rem < 27648) { int e = rem - 15360; int col = e / 24, j = e % 24;
        *(u64*)&P.ZSt[(size_t)m * 524288 + col * 1024 + 1000 + j] = 0; }
      else { int e = rem - 27648; int col = e / 24, j = e % 24;
        *(u64*)&P.SZ1t[(size_t)m * 524288 + col * 1024 + 1000 + j] = 0; }
      return;
    }
    return;
  }
  // ---- aux path: 1 elem ----
  int idx = (int)(tid - 2075904);
  if (idx < 384000) {        // BiG[mode][n*128+o]
    int mode = idx / 128000, rem = idx % 128000;
    int n = rem >> 7, o = rem & 127;
    const float* emb = (mode == 0) ? P.e0 : (mode == 1) ? P.e1 : P.e2;
    float s = 0.f;
#pragma unroll
    for (int d = 0; d < 16; ++d)
      s += emb[n * 16 + d] * P.me[mode * 16 + d] * P.Bg[d * 128 + o];
    P.BiG[idx] = s; return;
  }
  idx -= 384000;
  if (idx < 192000) {        // BiU[mode][n*64+o]
    int mode = idx / 64000, rem = idx % 64000;
    int n = rem >> 6, o = rem & 63;
    const float* emb = (mode == 0) ? P.e0 : (mode == 1) ? P.e1 : P.e2;
    float s = 0.f;
#pragma unroll
    for (int d = 0; d < 16; ++d)
      s += emb[n * 16 + d] * P.me[mode * 16 + d] * P.Bu[d * 64 + o];
    P.BiU[idx] = s; return;
  }
  idx -= 192000;
  if (idx < 524288) {        // BtG d-major: [(d*128+o)][k]
    int col = idx >> 8, k = idx & 255;
    int d = col >> 7, o = col & 127;
    P.BtG[idx] = (k < 240) ? (u16)f2bf(P.Wg[d * 30720 + k * 128 + o]) : (u16)0;
    return;
  }
  idx -= 524288;
  if (idx < 262144) {        // BtU d-major: [(d*64+o)][k]
    int col = idx >> 8, k = idx & 255;
    int d = col >> 6, o = col & 63;
    P.BtU[idx] = (k < 240) ? (u16)f2bf(P.Wu[d * 15360 + k * 64 + o]) : (u16)0;
  }
}

// ---------------------------------------------------------------------------
// cheb_v6: D[f][n] = alpha*sum_k A[f][k]*S16[n][k] (+beta*Res[f][n])
// Tile 32(f) x 64(n), BK=128, 8 barriered k-steps, 4 waves column-split.
// flags: 1=hasRes, 2=hasY, 4=hasAgX
// ---------------------------------------------------------------------------
struct ChebArgs2 {
  const u16* S16[3]; const u16* A[3]; const u16* Res[3];
  u16* Yt[3]; u16* AgA[3]; u16* AgX[3];
};

__global__ __launch_bounds__(256, 4) void cheb_v6(ChebArgs2 g, int fdiv, int agbase,
                                                  float alpha, float beta, int flags) {
  const int mode = blockIdx.z;
  const u16* __restrict__ Ab = g.A[mode];
  const u16* __restrict__ Sb = g.S16[mode];

  __shared__ u16 As[32 * 128];   // 8KB
  __shared__ u16 Bs[64 * 128];   // 16KB

  const int t = threadIdx.x;
  const int row0 = blockIdx.y * 32, n0 = blockIdx.x * 64;
  const int lane = t & 63, wid = t >> 6;
  const int l16 = lane & 15, quad = lane >> 4;
  const int wx = wid * 16;       // wave's 16-col group

  f32x4 acc[2];
#pragma unroll
  for (int a = 0; a < 2; ++a) acc[a] = (f32x4){0.f, 0.f, 0.f, 0.f};

  for (int k0 = 0; k0 < 1024; k0 += 128) {
#pragma unroll
    for (int p = 0; p < 2; ++p) {  // A: 32x128 = 512 chunks
      int idx = p * 256 + t; int row = idx >> 4; int cs = (idx & 15) ^ (row & 7);
      glds16(Ab + (size_t)(row0 + row) * 1024 + k0 + cs * 8, &As[idx * 8]);
    }
#pragma unroll
    for (int p = 0; p < 4; ++p) {  // B: 64x128 = 1024 chunks
      int idx = p * 256 + t; int row = idx >> 4; int cs = (idx & 15) ^ (row & 7);
      glds16(Sb + (size_t)(n0 + row) * 1024 + k0 + cs * 8, &Bs[idx * 8]);
    }
    __syncthreads();
    s16x8 af[2][4], bf[4];
#pragma unroll
    for (int mi = 0; mi < 2; ++mi) {
      int row = mi * 16 + l16;
#pragma unroll
      for (int ks = 0; ks < 4; ++ks) {
        int cl = (ks * 4 + quad) ^ (row & 7);
        af[mi][ks] = *(const s16x8*)&As[row * 128 + cl * 8];
      }
    }
    {
      int row = wx + l16;
#pragma unroll
      for (int ks = 0; ks < 4; ++ks) {
        int cl = (ks * 4 + quad) ^ (row & 7);
        bf[ks] = *(const s16x8*)&Bs[row * 128 + cl * 8];
      }
    }
#pragma unroll
    for (int ks = 0; ks < 4; ++ks)
#pragma unroll
      for (int mi = 0; mi < 2; ++mi)
        acc[mi] = __builtin_amdgcn_mfma_f32_16x16x32_bf16(af[mi][ks], bf[ks], acc[mi], 0, 0, 0);
    __syncthreads();
  }

#pragma unroll
  for (int mi = 0; mi < 2; ++mi) {
    int frow0 = row0 + mi * 16 + quad * 4;
    int b = frow0 / fdiv, c0 = frow0 - b * fdiv;
    int n = n0 + wx + l16;
    if (n < 1000) {
      u16 pk[4];
#pragma unroll
      for (int r = 0; r < 4; ++r) {
        float v = alpha * acc[mi][r];
        if (flags & 1) v += beta * bf2f(g.Res[mode][(size_t)(frow0 + r) * 1024 + n]);
        u16 h = (u16)f2bf(v);
        pk[r] = h;
        if (flags & 2) g.Yt[mode][(size_t)(frow0 + r) * 1024 + n] = h;
      }
      u64 pv = (u64)pk[0] | ((u64)pk[1] << 16) | ((u64)pk[2] << 32) | ((u64)pk[3] << 48);
      *(u64*)&g.AgA[mode][(size_t)(n * 8 + b) * 256 + agbase + c0] = pv;
      if ((flags & 4) && c0 < 16)
        *(u64*)&g.AgX[mode][(size_t)(n * 8 + b) * 256 + agbase + c0] = pv;
    }
  }
}

// ---------------------------------------------------------------------------
struct Meta3Args {
  const u16* Ag;        // [3][8000][256]
  const u16* Bt;        // [O*16][256] d-major
  const float* emb[3];
  const float* me;
  const float* Bias;    // [3][1000][O]
  const float* state[3];
  u16* ZSt;             // [3][512][1024]
  u16* AgU;             // [3][8000][256]
  float* Rb;            // [3][8000][64]
  float* out;
};

// ---------------------------------------------------------------------------
// meta3g (gate, 512 threads): block = 128 rows x 64 cols (oc=blockIdx.x),
// 8 waves in 4x2 (32r x 32c each). A staged in 2 phases through the 32KB
// buffer, hoisted to afr[2][8] per wave (AGPR-resident). 16 d-tiles of B
// (32KB each) single-buffered with __syncthreads: each stage now feeds
// 2x the MFMAs vs the 64-row block; gate B traffic halves.
// Grid (2, 63, 3) = 378 blocks; by=62 tail rows guarded (OOB A reads land
// in the adjacent AgU region - mapped, outputs guarded).
// ---------------------------------------------------------------------------
__global__ __launch_bounds__(512, 8) void meta3g(Meta3Args A, int O) {
  const int mode = blockIdx.z;
  const int row0 = blockIdx.y * 128;
  const int oc = blockIdx.x;
  const int ocbase = oc * 64;

  __shared__ u16 Bs[64 * 256];   // 32KB
  __shared__ float ewS[16][17];

  const int t = threadIdx.x;
  if (t < 256) {
    int nl = t >> 4, d = t & 15;
    int n = (row0 >> 3) + nl;
    ewS[nl][d] = (n < 1000) ? A.emb[mode][n * 16 + d] * A.me[mode * 16 + d] : 0.f;
  }

  const int lane = t & 63, wid = t >> 6;       // wid 0..7
  const int l16 = lane & 15, quad = lane >> 4;
  const int wy = (wid >> 1) * 32;              // 0,32,64,96
  const int wx = (wid & 1) * 32;               // 0,32
  const u16* Agm = A.Ag + (size_t)mode * 2048000;

  // A prologue: 2 phases of 64 rows through Bs; each wave hoists in its phase
  s16x8 afr[2][8];
#pragma unroll
  for (int ph = 0; ph < 2; ++ph) {
#pragma unroll
    for (int p = 0; p < 4; ++p) {
      int idx = p * 512 + t; int row = idx >> 5; int cs = (idx & 31) ^ (row & 7);
      glds16(Agm + (size_t)(row0 + ph * 64 + row) * 256 + cs * 8, &Bs[idx * 8]);
    }
    __syncthreads();
    if ((wy >> 6) == ph) {
      int rloc = wy & 63;
#pragma unroll
      for (int mi = 0; mi < 2; ++mi) {
        int row = rloc + mi * 16 + l16;
#pragma unroll
        for (int ki = 0; ki < 8; ++ki) {
          int cl = (ki * 4 + quad) ^ (row & 7);
          afr[mi][ki] = *(const s16x8*)&Bs[row * 256 + cl * 8];
        }
      }
    }
    __syncthreads();
  }

  f32x4 outacc[2][2];
#pragma unroll
  for (int a = 0; a < 2; ++a)
#pragma unroll
    for (int b = 0; b < 2; ++b) outacc[a][b] = (f32x4){0.f, 0.f, 0.f, 0.f};

  for (int tl = 0; tl < 16; ++tl) {           // tl == d
    const int brow0 = tl * O + ocbase;
#pragma unroll
    for (int p = 0; p < 4; ++p) {
      int idx = p * 512 + t; int row = idx >> 5; int cs = (idx & 31) ^ (row & 7);
      glds16(A.Bt + (size_t)(brow0 + row) * 256 + cs * 8, &Bs[idx * 8]);
    }
    __syncthreads();   // B tile staged

    f32x4 acc[2][2];
#pragma unroll
    for (int a = 0; a < 2; ++a)
#pragma unroll
      for (int b = 0; b < 2; ++b) acc[a][b] = (f32x4){0.f, 0.f, 0.f, 0.f};

#pragma unroll
    for (int ki = 0; ki < 8; ++ki) {
      s16x8 bfr[2];
#pragma unroll
      for (int ni = 0; ni < 2; ++ni) {
        int row = wx + ni * 16 + l16;
        int cl = (ki * 4 + quad) ^ (row & 7);
        bfr[ni] = *(const s16x8*)&Bs[row * 256 + cl * 8];
      }
#pragma unroll
      for (int mi = 0; mi < 2; ++mi)
#pragma unroll
        for (int ni = 0; ni < 2; ++ni)
          acc[mi][ni] = __builtin_amdgcn_mfma_f32_16x16x32_bf16(afr[mi][ki], bfr[ni], acc[mi][ni], 0, 0, 0);
    }

    // fold d: outacc += ew[n,d] * acc
#pragma unroll
    for (int mi = 0; mi < 2; ++mi) {
      int nl = (wy + mi * 16 + quad * 4) >> 3;
      float s = ewS[nl][tl];
#pragma unroll
      for (int ni = 0; ni < 2; ++ni)
#pragma unroll
        for (int r = 0; r < 4; ++r)
          outacc[mi][ni][r] += s * acc[mi][ni][r];
    }
    __syncthreads();   // Bs reads retired before next tile's stage
  }

  // epilogue (gate): bias + sigmoid + ZSt/AgU/Rb writes, row-guarded
#pragma unroll
  for (int mi = 0; mi < 2; ++mi)
#pragma unroll
    for (int ni = 0; ni < 2; ++ni)
#pragma unroll
      for (int r = 0; r < 4; ++r) {
        int row = row0 + wy + mi * 16 + quad * 4 + r;
        if (row < 8000) {
          int n = row >> 3, b = row & 7;
          int o = ocbase + wx + ni * 16 + l16;
          float pre = outacc[mi][ni][r] + A.Bias[(size_t)mode * 1000 * O + n * O + o];
          float sg = 1.f / (1.f + __expf(-pre));
          if (o < 64) {
            float st = A.state[mode][(b * 1000 + n) * 64 + o];
            float zs = sg * st;
            A.ZSt[(size_t)mode * 524288 + (size_t)(b * 64 + o) * 1024 + n] = (u16)f2bf(zs);
            A.AgU[(size_t)mode * 2048000 + (size_t)row * 256 + 16 + o] = (u16)f2bf(zs);
          } else {
            A.Rb[(size_t)mode * 512000 + row * 64 + (o - 64)] = sg;
          }
        }
      }
}

// ---------------------------------------------------------------------------
// meta3u (update, split-d, v16): grid (2,125,3); dh=blockIdx.x covers d in
// [8dh, 8dh+8). Writes raw f32 partials to Pacc (Ag overlay).
// ---------------------------------------------------------------------------
__global__ __launch_bounds__(256, 4) void meta3u(Meta3Args A, float* Pacc) {
  const int mode = blockIdx.z;
  const int row0 = blockIdx.y * 64;
  const int n0 = row0 >> 3;
  const int dh = blockIdx.x;          // d-half: 0 or 1

  __shared__ u16 Bs[64 * 256];
  __shared__ float ewS[8][17];

  const int t = threadIdx.x;
  if (t < 128) {
    int nl = t >> 4, d = t & 15;
    ewS[nl][d] = A.emb[mode][(n0 + nl) * 16 + d] * A.me[mode * 16 + d];
  }

  const int lane = t & 63, wid = t >> 6;
  const int l16 = lane & 15, quad = lane >> 4;
  const int wy = (wid >> 1) * 32, wx = (wid & 1) * 32;
  const u16* Agm = A.Ag + (size_t)mode * 2048000;

#pragma unroll
  for (int p = 0; p < 8; ++p) {
    int idx = p * 256 + t; int row = idx >> 5; int cs = (idx & 31) ^ (row & 7);
    glds16(Agm + (size_t)(row0 + row) * 256 + cs * 8, &Bs[idx * 8]);
  }
  __syncthreads();

  s16x8 afr[2][8];
#pragma unroll
  for (int mi = 0; mi < 2; ++mi) {
    int row = wy + mi * 16 + l16;
#pragma unroll
    for (int ki = 0; ki < 8; ++ki) {
      int cl = (ki * 4 + quad) ^ (row & 7);
      afr[mi][ki] = *(const s16x8*)&Bs[row * 256 + cl * 8];
    }
  }
  __syncthreads();

  f32x4 outacc[2][2];
#pragma unroll
  for (int a = 0; a < 2; ++a)
#pragma unroll
    for (int b = 0; b < 2; ++b) outacc[a][b] = (f32x4){0.f, 0.f, 0.f, 0.f};

  for (int tl = dh * 8; tl < dh * 8 + 8; ++tl) {
    const int brow0 = tl * 64;
#pragma unroll
    for (int p = 0; p < 8; ++p) {
      int idx = p * 256 + t; int row = idx >> 5; int cs = (idx & 31) ^ (row & 7);
      glds16(A.Bt + (size_t)(brow0 + row) * 256 + cs * 8, &Bs[idx * 8]);
    }
    __syncthreads();

    f32x4 acc[2][2];
#pragma unroll
    for (int a = 0; a < 2; ++a)
#pragma unroll
      for (int b = 0; b < 2; ++b) acc[a][b] = (f32x4){0.f, 0.f, 0.f, 0.f};

#pragma unroll
    for (int ki = 0; ki < 8; ++ki) {
      s16x8 bfr[2];
#pragma unroll
      for (int ni = 0; ni < 2; ++ni) {
        int row = wx + ni * 16 + l16;
        int cl = (ki * 4 + quad) ^ (row & 7);
        bfr[ni] = *(const s16x8*)&Bs[row * 256 + cl * 8];
      }
#pragma unroll
      for (int mi = 0; mi < 2; ++mi)
#pragma unroll
        for (int ni = 0; ni < 2; ++ni)
          acc[mi][ni] = __builtin_amdgcn_mfma_f32_16x16x32_bf16(afr[mi][ki], bfr[ni], acc[mi][ni], 0, 0, 0);
    }

#pragma unroll
    for (int mi = 0; mi < 2; ++mi) {
      int nl = (wy + mi * 16 + quad * 4) >> 3;
      float s = ewS[nl][tl];
#pragma unroll
      for (int ni = 0; ni < 2; ++ni)
#pragma unroll
        for (int r = 0; r < 4; ++r)
          outacc[mi][ni][r] += s * acc[mi][ni][r];
    }
    __syncthreads();
  }

  // write raw partials: Pacc[((dh*3+mode)*8000 + row)*64 + o]
#pragma unroll
  for (int mi = 0; mi < 2; ++mi)
#pragma unroll
    for (int ni = 0; ni < 2; ++ni)
#pragma unroll
      for (int r = 0; r < 4; ++r) {
        int row = row0 + wy + mi * 16 + quad * 4 + r;
        int o = wx + ni * 16 + l16;
        Pacc[((size_t)(dh * 3 + mode) * 8000 + row) * 64 + o] = outacc[mi][ni][r];
      }
}

// ---------------------------------------------------------------------------
// epi_u: out = r*state + (1-r)*tanh(p0+p1+BiU). 3*8000*64 = 1.536M threads.
// ---------------------------------------------------------------------------
__global__ void epi_u(const float* __restrict__ Pacc, const float* __restrict__ BiU,
                      const float* __restrict__ Rb,
                      const float* __restrict__ st0, const float* __restrict__ st1,
                      const float* __restrict__ st2, float* __restrict__ out) {
  int idx = blockIdx.x * blockDim.x + threadIdx.x;
  if (idx >= 1536000) return;
  int mode = idx / 512000, rem = idx % 512000;
  int row = rem >> 6, o = rem & 63;
  int n = row >> 3, b = row & 7;
  float pre = Pacc[((size_t)mode * 8000 + row) * 64 + o] +
              Pacc[((size_t)(3 + mode) * 8000 + row) * 64 + o] +
              BiU[(size_t)mode * 64000 + n * 64 + o];
  float hc = tanhf(pre);
  float rr = Rb[(size_t)mode * 512000 + row * 64 + o];
  const float* st = (mode == 0) ? st0 : (mode == 1) ? st1 : st2;
  out[(size_t)mode * 512000 + (b * 1000 + n) * 64 + o] =
      rr * st[(b * 1000 + n) * 64 + o] + (1.f - rr) * hc;
}

// ---------------------------------------------------------------------------
extern "C" void kernel_launch(void* const* d_in, const int* in_sizes, int n_in,
                              void* d_out, int out_size, void* d_ws, size_t ws_size,
                              hipStream_t stream) {
  const float* x[3]   = {(const float*)d_in[0], (const float*)d_in[1], (const float*)d_in[2]};
  const float* st[3]  = {(const float*)d_in[3], (const float*)d_in[4], (const float*)d_in[5]};
  const float* S[3]   = {(const float*)d_in[6], (const float*)d_in[7], (const float*)d_in[8]};
  const float* emb[3] = {(const float*)d_in[9], (const float*)d_in[10], (const float*)d_in[11]};
  const float* me = (const float*)d_in[12];
  const float* Wg = (const float*)d_in[13];
  const float* Bg = (const float*)d_in[14];
  const float* Wu = (const float*)d_in[15];
  const float* Bu = (const float*)d_in[16];
  float* out = (float*)d_out;

  float* BiG = (float*)d_ws;            // 3*1000*128
  float* BiU = BiG + 384000;            // 3*1000*64
  float* Rb  = BiU + 192000;            // 3*8000*64
  u16* S16 = (u16*)(Rb + 1536000);      // 3*1024*1024
  u16* Xt  = S16 + 3145728;             // 3*640*1024
  u16* T1t = Xt + 1966080;              // 3*640*1024
  u16* ZSt = T1t + 1966080;             // 3*512*1024
  u16* SZ1t= ZSt + 1572864;             // 3*512*1024
  u16* Ag  = SZ1t + 1572864;            // 3*8000*256
  u16* AgU = Ag + 6144000;              // 3*8000*256
  u16* BtG = AgU + 6144000;             // 2048*256
  u16* BtU = BtG + 524288;              // 1024*256
  float* PaccU = (float*)Ag;            // overlay: [2][3][8000][64] f32

  {
    PrepAuxArgs P;
    for (int m = 0; m < 3; ++m) { P.x[m] = x[m]; P.st[m] = st[m]; P.S[m] = S[m]; }
    P.S16 = S16; P.Xt = Xt; P.Ag = Ag; P.AgU = AgU; P.T1t = T1t; P.ZSt = ZSt; P.SZ1t = SZ1t;
    P.e0 = emb[0]; P.e1 = emb[1]; P.e2 = emb[2]; P.me = me;
    P.Bg = Bg; P.Bu = Bu; P.Wg = Wg; P.Wu = Wu;
    P.BiG = BiG; P.BiU = BiU; P.BtG = BtG; P.BtU = BtU;
    prep_aux<<<13431, 256, 0, stream>>>(P);
  }

  // cheb1: T1t = Xt @ S^T -> T1t + Ag[80..159] (+AgU x-part)
  {
    ChebArgs2 a;
    for (int m = 0; m < 3; ++m) {
      a.S16[m] = S16 + (size_t)m * 1048576; a.A[m] = Xt + (size_t)m * 655360;
      a.Res[m] = nullptr; a.Yt[m] = T1t + (size_t)m * 655360;
      a.AgA[m] = Ag + (size_t)m * 2048000; a.AgX[m] = AgU + (size_t)m * 2048000;
    }
    cheb_v6<<<dim3(16, 20, 3), 256, 0, stream>>>(a, 80, 80, 1.f, 0.f, 2 | 4);
  }
  // cheb2: T2t = 2*T1t @ S^T - Xt -> Ag[160..239] (+AgU x-part)
  {
    ChebArgs2 a;
    for (int m = 0; m < 3; ++m) {
      a.S16[m] = S16 + (size_t)m * 1048576; a.A[m] = T1t + (size_t)m * 655360;
      a.Res[m] = Xt + (size_t)m * 655360; a.Yt[m] = nullptr;
      a.AgA[m] = Ag + (size_t)m * 2048000; a.AgX[m] = AgU + (size_t)m * 2048000;
    }
    cheb_v6<<<dim3(16, 20, 3), 256, 0, stream>>>(a, 80, 160, 2.f, -1.f, 1 | 4);
  }
  // gate meta (128-row blocks): reads Ag; writes ZSt + AgU[16..79] + Rb
  {
    Meta3Args a;
    a.Ag = Ag; a.Bt = BtG; a.me = me; a.Bias = BiG;
    a.ZSt = ZSt; a.AgU = AgU; a.Rb = Rb; a.out = out;
    for (int m = 0; m < 3; ++m) { a.emb[m] = emb[m]; a.state[m] = st[m]; }
    meta3g<<<dim3(2, 63, 3), 512, 0, stream>>>(a, 128);
  }
  // cheb3: SZ1t = ZSt @ S^T -> SZ1t + AgU[96..159]
  {
    ChebArgs2 a;
    for (int m = 0; m < 3; ++m) {
      a.S16[m] = S16 + (size_t)m * 1048576; a.A[m] = ZSt + (size_t)m * 524288;
      a.Res[m] = nullptr; a.Yt[m] = SZ1t + (size_t)m * 524288;
      a.AgA[m] = AgU + (size_t)m * 2048000; a.AgX[m] = nullptr;
    }
    cheb_v6<<<dim3(16, 16, 3), 256, 0, stream>>>(a, 64, 96, 1.f, 0.f, 2);
  }
  // cheb4: SZ2t = 2*SZ1t @ S^T - ZSt -> AgU[176..239]
  {
    ChebArgs2 a;
    for (int m = 0; m < 3; ++m) {
      a.S16[m] = S16 + (size_t)m * 1048576; a.A[m] = SZ1t + (size_t)m * 524288;
      a.Res[m] = ZSt + (size_t)m * 524288; a.Yt[m] = nullptr;
      a.AgA[m] = AgU + (size_t)m * 2048000; a.AgX[m] = nullptr;
    }
    cheb_v6<<<dim3(16, 16, 3), 256, 0, stream>>>(a, 64, 176, 2.f, -1.f, 1);
  }
  // update meta (split-d): reads AgU; writes PaccU partials (Ag overlay)
  {
    Meta3Args a;
    a.Ag = AgU; a.Bt = BtU; a.me = me; a.Bias = BiU;
    a.ZSt = ZSt; a.AgU = AgU; a.Rb = Rb; a.out = out;
    for (int m = 0; m < 3; ++m) { a.emb[m] = emb[m]; a.state[m] = st[m]; }
    meta3u<<<dim3(2, 125, 3), 256, 0, stream>>>(a, PaccU);
  }
  // update epilogue: out = r*state + (1-r)*tanh(p0+p1+BiU)
  epi_u<<<6000, 256, 0, stream>>>(PaccU, BiU, Rb, st[0], st[1], st[2], out);
}

// Round 15
// 251.697 us; speedup vs baseline: 1.4208x; 1.4208x over previous
//
#include <hip/hip_runtime.h>
#include <math.h>

// ---------------------------------------------------------------------------
// HimNet multimode v18. B=8,N=1000,CIN=16,H=64,D=16,K=3,XIN=80,K*XIN=240,2H=128
//
// v18 = v17 with meta3g's launch bounds FIXED: __launch_bounds__(512, 4).
// v17's (512, 8) demanded 8 waves/EU -> 64 VGPR/wave cap -> afr spilled
// (VGPR_Count=32, FETCH 305MB, 160us). ERRATA-15 trap: 2nd arg is waves/EU;
// for a 512-thread block, blocks/CU = w/2, so w=4 gives 2 blocks/CU at a
// 128-VGPR budget - the exact regime where v6's afr[2][8] stays
// AGPR-resident (64 VGPR + 64 AGPR).
// meta3g: 128 rows x 64 cols, 8 waves 4x2; B-tile traffic halves vs 64-row.
// update = split-d meta3u + epi_u (v16). cheb_v6 + prep_aux (v15/v14).
// ---------------------------------------------------------------------------

typedef __attribute__((ext_vector_type(8))) short s16x8;
typedef __attribute__((ext_vector_type(4))) float f32x4;
typedef unsigned short u16;
typedef unsigned int u32;
typedef unsigned long long u64;

__device__ __forceinline__ u32 f2bf(float f) {
  union { float f; u32 u; } v; v.f = f;
  return (v.u + 0x7FFFu + ((v.u >> 16) & 1u)) >> 16;  // RNE
}
__device__ __forceinline__ float bf2f(u16 h) {
  union { u32 u; float f; } v; v.u = (u32)h << 16; return v.f;
}
__device__ __forceinline__ u64 pk4(float a, float b, float c, float d) {
  return (u64)f2bf(a) | ((u64)f2bf(b) << 16) | ((u64)f2bf(c) << 32) |
         ((u64)f2bf(d) << 48);
}
__device__ __forceinline__ void glds16(const u16* g, u16* l) {
  __builtin_amdgcn_global_load_lds(
      (const __attribute__((address_space(1))) void*)g,
      (__attribute__((address_space(3))) void*)l, 16, 0, 0);
}

// ---------------------------------------------------------------------------
// prep_aux: prep (4 elems/thread) + aux (1 elem/thread) in one launch.
// ---------------------------------------------------------------------------
#define E0 3145728
#define E1 1966080
#define E2 1920000
#define E3 384000
#define E4 384000
#define E5 384000
#define E6 119808
// prep total = 8303616 elems = 2075904 threads; aux total = 1362432 threads
// grid = 8109 + 5322 = 13431 blocks of 256

struct PrepAuxArgs {
  const float* x[3]; const float* st[3]; const float* S[3];
  u16 *S16, *Xt, *Ag, *AgU, *T1t, *ZSt, *SZ1t;
  const float *e0, *e1, *e2, *me, *Bg, *Bu, *Wg, *Wu;
  float *BiG, *BiU; u16 *BtG, *BtU;
};

__global__ void prep_aux(PrepAuxArgs P) {
  long tid = (long)blockIdx.x * 256 + threadIdx.x;
  if (tid < 2075904) {        // ---- prep path: 4 elems ----
    long idx = tid * 4;
    if (idx < E0) {  // S16 incl pads: 4 consecutive k, same n
      int m = (int)(idx >> 20); int rem = (int)(idx & 1048575);
      int n = rem >> 10, k = rem & 1023;
      u64 pv = 0;
      if (n < 1000 && k < 1000) {
        f32x4 v = *(const f32x4*)&P.S[m][n * 1000 + k];
        pv = pk4(v[0], v[1], v[2], v[3]);
      }
      *(u64*)&P.S16[(size_t)m * 1048576 + rem] = pv; return;
    }
    idx -= E0;
    if (idx < E1) {  // Xt: 4 consecutive nn, same col
      int m = (int)(idx / 655360); int rem = (int)(idx % 655360);
      int col = rem >> 10, nn = rem & 1023;
      int b = col / 80, c = col % 80;
      u64 pv = 0;
      if (nn < 1000) {
        float f[4];
#pragma unroll
        for (int j = 0; j < 4; ++j)
          f[j] = (c < 16) ? P.x[m][(b * 1000 + nn + j) * 16 + c]
                          : P.st[m][(b * 1000 + nn + j) * 64 + c - 16];
        pv = pk4(f[0], f[1], f[2], f[3]);
      }
      *(u64*)&P.Xt[(size_t)m * 655360 + rem] = pv; return;
    }
    idx -= E1;
    if (idx < E2) {  // Ag kc0: 4 consecutive c, same r
      int m = (int)(idx / 640000); int rem = (int)(idx % 640000);
      int r = rem / 80, c = rem % 80;
      int n = r >> 3, b = r & 7;
      f32x4 v = (c < 16) ? *(const f32x4*)&P.x[m][(b * 1000 + n) * 16 + c]
                         : *(const f32x4*)&P.st[m][(b * 1000 + n) * 64 + c - 16];
      *(u64*)&P.Ag[(size_t)m * 2048000 + (size_t)r * 256 + c] =
          pk4(v[0], v[1], v[2], v[3]);
      return;
    }
    idx -= E2;
    if (idx < E3) {  // Ag K-pad 240..255
      int m = (int)(idx / 128000); int rem = (int)(idx % 128000);
      int r = rem / 16, c = 240 + rem % 16;
      *(u64*)&P.Ag[(size_t)m * 2048000 + (size_t)r * 256 + c] = 0; return;
    }
    idx -= E3;
    if (idx < E4) {  // AgU kc0 x-part (cols 0..15)
      int m = (int)(idx / 128000); int rem = (int)(idx % 128000);
      int r = rem / 16, c = rem % 16;
      int n = r >> 3, b = r & 7;
      f32x4 v = *(const f32x4*)&P.x[m][(b * 1000 + n) * 16 + c];
      *(u64*)&P.AgU[(size_t)m * 2048000 + (size_t)r * 256 + c] =
          pk4(v[0], v[1], v[2], v[3]);
      return;
    }
    idx -= E4;
    if (idx < E5) {  // AgU K-pad
      int m = (int)(idx / 128000); int rem = (int)(idx % 128000);
      int r = rem / 16, c = 240 + rem % 16;
      *(u64*)&P.AgU[(size_t)m * 2048000 + (size_t)r * 256 + c] = 0; return;
    }
    idx -= E5;
    if (idx < E6) {  // n-pad rows (k=1000..1023) of T1t/ZSt/SZ1t
      int m = (int)(idx / 39936); int rem = (int)(idx % 39936);
      if (rem < 15360) { int col = rem / 24, j = rem % 24;
        *(u64*)&P.T1t[(size_t)m * 655360 + col * 1024 + 1000 + j] = 0; }
      else if (rem < 27648) { int e = rem - 15360; int col = e / 24, j = e % 24;
        *(u64*)&P.ZSt[(size_t)m * 524288 + col * 1024 + 1000 + j] = 0; }
      else { int e = rem - 27648; int col = e / 24, j = e % 24;
        *(u64*)&P.SZ1t[(size_t)m * 524288 + col * 1024 + 1000 + j] = 0; }
      return;
    }
    return;
  }
  // ---- aux path: 1 elem ----
  int idx = (int)(tid - 2075904);
  if (idx < 384000) {        // BiG[mode][n*128+o]
    int mode = idx / 128000, rem = idx % 128000;
    int n = rem >> 7, o = rem & 127;
    const float* emb = (mode == 0) ? P.e0 : (mode == 1) ? P.e1 : P.e2;
    float s = 0.f;
#pragma unroll
    for (int d = 0; d < 16; ++d)
      s += emb[n * 16 + d] * P.me[mode * 16 + d] * P.Bg[d * 128 + o];
    P.BiG[idx] = s; return;
  }
  idx -= 384000;
  if (idx < 192000) {        // BiU[mode][n*64+o]
    int mode = idx / 64000, rem = idx % 64000;
    int n = rem >> 6, o = rem & 63;
    const float* emb = (mode == 0) ? P.e0 : (mode == 1) ? P.e1 : P.e2;
    float s = 0.f;
#pragma unroll
    for (int d = 0; d < 16; ++d)
      s += emb[n * 16 + d] * P.me[mode * 16 + d] * P.Bu[d * 64 + o];
    P.BiU[idx] = s; return;
  }
  idx -= 192000;
  if (idx < 524288) {        // BtG d-major: [(d*128+o)][k]
    int col = idx >> 8, k = idx & 255;
    int d = col >> 7, o = col & 127;
    P.BtG[idx] = (k < 240) ? (u16)f2bf(P.Wg[d * 30720 + k * 128 + o]) : (u16)0;
    return;
  }
  idx -= 524288;
  if (idx < 262144) {        // BtU d-major: [(d*64+o)][k]
    int col = idx >> 8, k = idx & 255;
    int d = col >> 6, o = col & 63;
    P.BtU[idx] = (k < 240) ? (u16)f2bf(P.Wu[d * 15360 + k * 64 + o]) : (u16)0;
  }
}

// ---------------------------------------------------------------------------
// cheb_v6: D[f][n] = alpha*sum_k A[f][k]*S16[n][k] (+beta*Res[f][n])
// Tile 32(f) x 64(n), BK=128, 8 barriered k-steps, 4 waves column-split.
// flags: 1=hasRes, 2=hasY, 4=hasAgX
// ---------------------------------------------------------------------------
struct ChebArgs2 {
  const u16* S16[3]; const u16* A[3]; const u16* Res[3];
  u16* Yt[3]; u16* AgA[3]; u16* AgX[3];
};

__global__ __launch_bounds__(256, 4) void cheb_v6(ChebArgs2 g, int fdiv, int agbase,
                                                  float alpha, float beta, int flags) {
  const int mode = blockIdx.z;
  const u16* __restrict__ Ab = g.A[mode];
  const u16* __restrict__ Sb = g.S16[mode];

  __shared__ u16 As[32 * 128];   // 8KB
  __shared__ u16 Bs[64 * 128];   // 16KB

  const int t = threadIdx.x;
  const int row0 = blockIdx.y * 32, n0 = blockIdx.x * 64;
  const int lane = t & 63, wid = t >> 6;
  const int l16 = lane & 15, quad = lane >> 4;
  const int wx = wid * 16;       // wave's 16-col group

  f32x4 acc[2];
#pragma unroll
  for (int a = 0; a < 2; ++a) acc[a] = (f32x4){0.f, 0.f, 0.f, 0.f};

  for (int k0 = 0; k0 < 1024; k0 += 128) {
#pragma unroll
    for (int p = 0; p < 2; ++p) {  // A: 32x128 = 512 chunks
      int idx = p * 256 + t; int row = idx >> 4; int cs = (idx & 15) ^ (row & 7);
      glds16(Ab + (size_t)(row0 + row) * 1024 + k0 + cs * 8, &As[idx * 8]);
    }
#pragma unroll
    for (int p = 0; p < 4; ++p) {  // B: 64x128 = 1024 chunks
      int idx = p * 256 + t; int row = idx >> 4; int cs = (idx & 15) ^ (row & 7);
      glds16(Sb + (size_t)(n0 + row) * 1024 + k0 + cs * 8, &Bs[idx * 8]);
    }
    __syncthreads();
    s16x8 af[2][4], bf[4];
#pragma unroll
    for (int mi = 0; mi < 2; ++mi) {
      int row = mi * 16 + l16;
#pragma unroll
      for (int ks = 0; ks < 4; ++ks) {
        int cl = (ks * 4 + quad) ^ (row & 7);
        af[mi][ks] = *(const s16x8*)&As[row * 128 + cl * 8];
      }
    }
    {
      int row = wx + l16;
#pragma unroll
      for (int ks = 0; ks < 4; ++ks) {
        int cl = (ks * 4 + quad) ^ (row & 7);
        bf[ks] = *(const s16x8*)&Bs[row * 128 + cl * 8];
      }
    }
#pragma unroll
    for (int ks = 0; ks < 4; ++ks)
#pragma unroll
      for (int mi = 0; mi < 2; ++mi)
        acc[mi] = __builtin_amdgcn_mfma_f32_16x16x32_bf16(af[mi][ks], bf[ks], acc[mi], 0, 0, 0);
    __syncthreads();
  }

#pragma unroll
  for (int mi = 0; mi < 2; ++mi) {
    int frow0 = row0 + mi * 16 + quad * 4;
    int b = frow0 / fdiv, c0 = frow0 - b * fdiv;
    int n = n0 + wx + l16;
    if (n < 1000) {
      u16 pk[4];
#pragma unroll
      for (int r = 0; r < 4; ++r) {
        float v = alpha * acc[mi][r];
        if (flags & 1) v += beta * bf2f(g.Res[mode][(size_t)(frow0 + r) * 1024 + n]);
        u16 h = (u16)f2bf(v);
        pk[r] = h;
        if (flags & 2) g.Yt[mode][(size_t)(frow0 + r) * 1024 + n] = h;
      }
      u64 pv = (u64)pk[0] | ((u64)pk[1] << 16) | ((u64)pk[2] << 32) | ((u64)pk[3] << 48);
      *(u64*)&g.AgA[mode][(size_t)(n * 8 + b) * 256 + agbase + c0] = pv;
      if ((flags & 4) && c0 < 16)
        *(u64*)&g.AgX[mode][(size_t)(n * 8 + b) * 256 + agbase + c0] = pv;
    }
  }
}

// ---------------------------------------------------------------------------
struct Meta3Args {
  const u16* Ag;        // [3][8000][256]
  const u16* Bt;        // [O*16][256] d-major
  const float* emb[3];
  const float* me;
  const float* Bias;    // [3][1000][O]
  const float* state[3];
  u16* ZSt;             // [3][512][1024]
  u16* AgU;             // [3][8000][256]
  float* Rb;            // [3][8000][64]
  float* out;
};

// ---------------------------------------------------------------------------
// meta3g (gate, 512 threads, __launch_bounds__(512,4) = 2 blocks/CU at a
// 128-VGPR/wave budget): block = 128 rows x 64 cols (oc=blockIdx.x),
// 8 waves in 4x2 (32r x 32c each). A staged in 2 phases through the 32KB
// buffer, hoisted to afr[2][8] per wave (AGPR-resident at this budget).
// 16 d-tiles of B (32KB each) single-buffered with __syncthreads: each
// stage feeds 2x the MFMAs vs the 64-row block; gate B traffic halves.
// Grid (2, 63, 3) = 378 blocks; by=62 tail rows guarded.
// ---------------------------------------------------------------------------
__global__ __launch_bounds__(512, 4) void meta3g(Meta3Args A, int O) {
  const int mode = blockIdx.z;
  const int row0 = blockIdx.y * 128;
  const int oc = blockIdx.x;
  const int ocbase = oc * 64;

  __shared__ u16 Bs[64 * 256];   // 32KB
  __shared__ float ewS[16][17];

  const int t = threadIdx.x;
  if (t < 256) {
    int nl = t >> 4, d = t & 15;
    int n = (row0 >> 3) + nl;
    ewS[nl][d] = (n < 1000) ? A.emb[mode][n * 16 + d] * A.me[mode * 16 + d] : 0.f;
  }

  const int lane = t & 63, wid = t >> 6;       // wid 0..7
  const int l16 = lane & 15, quad = lane >> 4;
  const int wy = (wid >> 1) * 32;              // 0,32,64,96
  const int wx = (wid & 1) * 32;               // 0,32
  const u16* Agm = A.Ag + (size_t)mode * 2048000;

  // A prologue: 2 phases of 64 rows through Bs; each wave hoists in its phase
  s16x8 afr[2][8];
#pragma unroll
  for (int ph = 0; ph < 2; ++ph) {
#pragma unroll
    for (int p = 0; p < 4; ++p) {
      int idx = p * 512 + t; int row = idx >> 5; int cs = (idx & 31) ^ (row & 7);
      glds16(Agm + (size_t)(row0 + ph * 64 + row) * 256 + cs * 8, &Bs[idx * 8]);
    }
    __syncthreads();
    if ((wy >> 6) == ph) {
      int rloc = wy & 63;
#pragma unroll
      for (int mi = 0; mi < 2; ++mi) {
        int row = rloc + mi * 16 + l16;
#pragma unroll
        for (int ki = 0; ki < 8; ++ki) {
          int cl = (ki * 4 + quad) ^ (row & 7);
          afr[mi][ki] = *(const s16x8*)&Bs[row * 256 + cl * 8];
        }
      }
    }
    __syncthreads();
  }

  f32x4 outacc[2][2];
#pragma unroll
  for (int a = 0; a < 2; ++a)
#pragma unroll
    for (int b = 0; b < 2; ++b) outacc[a][b] = (f32x4){0.f, 0.f, 0.f, 0.f};

  for (int tl = 0; tl < 16; ++tl) {           // tl == d
    const int brow0 = tl * O + ocbase;
#pragma unroll
    for (int p = 0; p < 4; ++p) {
      int idx = p * 512 + t; int row = idx >> 5; int cs = (idx & 31) ^ (row & 7);
      glds16(A.Bt + (size_t)(brow0 + row) * 256 + cs * 8, &Bs[idx * 8]);
    }
    __syncthreads();   // B tile staged

    f32x4 acc[2][2];
#pragma unroll
    for (int a = 0; a < 2; ++a)
#pragma unroll
      for (int b = 0; b < 2; ++b) acc[a][b] = (f32x4){0.f, 0.f, 0.f, 0.f};

#pragma unroll
    for (int ki = 0; ki < 8; ++ki) {
      s16x8 bfr[2];
#pragma unroll
      for (int ni = 0; ni < 2; ++ni) {
        int row = wx + ni * 16 + l16;
        int cl = (ki * 4 + quad) ^ (row & 7);
        bfr[ni] = *(const s16x8*)&Bs[row * 256 + cl * 8];
      }
#pragma unroll
      for (int mi = 0; mi < 2; ++mi)
#pragma unroll
        for (int ni = 0; ni < 2; ++ni)
          acc[mi][ni] = __builtin_amdgcn_mfma_f32_16x16x32_bf16(afr[mi][ki], bfr[ni], acc[mi][ni], 0, 0, 0);
    }

    // fold d: outacc += ew[n,d] * acc
#pragma unroll
    for (int mi = 0; mi < 2; ++mi) {
      int nl = (wy + mi * 16 + quad * 4) >> 3;
      float s = ewS[nl][tl];
#pragma unroll
      for (int ni = 0; ni < 2; ++ni)
#pragma unroll
        for (int r = 0; r < 4; ++r)
          outacc[mi][ni][r] += s * acc[mi][ni][r];
    }
    __syncthreads();   // Bs reads retired before next tile's stage
  }

  // epilogue (gate): bias + sigmoid + ZSt/AgU/Rb writes, row-guarded
#pragma unroll
  for (int mi = 0; mi < 2; ++mi)
#pragma unroll
    for (int ni = 0; ni < 2; ++ni)
#pragma unroll
      for (int r = 0; r < 4; ++r) {
        int row = row0 + wy + mi * 16 + quad * 4 + r;
        if (row < 8000) {
          int n = row >> 3, b = row & 7;
          int o = ocbase + wx + ni * 16 + l16;
          float pre = outacc[mi][ni][r] + A.Bias[(size_t)mode * 1000 * O + n * O + o];
          float sg = 1.f / (1.f + __expf(-pre));
          if (o < 64) {
            float st = A.state[mode][(b * 1000 + n) * 64 + o];
            float zs = sg * st;
            A.ZSt[(size_t)mode * 524288 + (size_t)(b * 64 + o) * 1024 + n] = (u16)f2bf(zs);
            A.AgU[(size_t)mode * 2048000 + (size_t)row * 256 + 16 + o] = (u16)f2bf(zs);
          } else {
            A.Rb[(size_t)mode * 512000 + row * 64 + (o - 64)] = sg;
          }
        }
      }
}

// ---------------------------------------------------------------------------
// meta3u (update, split-d, v16): grid (2,125,3); dh=blockIdx.x covers d in
// [8dh, 8dh+8). Writes raw f32 partials to Pacc (Ag overlay).
// ---------------------------------------------------------------------------
__global__ __launch_bounds__(256, 4) void meta3u(Meta3Args A, float* Pacc) {
  const int mode = blockIdx.z;
  const int row0 = blockIdx.y * 64;
  const int n0 = row0 >> 3;
  const int dh = blockIdx.x;          // d-half: 0 or 1

  __shared__ u16 Bs[64 * 256];
  __shared__ float ewS[8][17];

  const int t = threadIdx.x;
  if (t < 128) {
    int nl = t >> 4, d = t & 15;
    ewS[nl][d] = A.emb[mode][(n0 + nl) * 16 + d] * A.me[mode * 16 + d];
  }

  const int lane = t & 63, wid = t >> 6;
  const int l16 = lane & 15, quad = lane >> 4;
  const int wy = (wid >> 1) * 32, wx = (wid & 1) * 32;
  const u16* Agm = A.Ag + (size_t)mode * 2048000;

#pragma unroll
  for (int p = 0; p < 8; ++p) {
    int idx = p * 256 + t; int row = idx >> 5; int cs = (idx & 31) ^ (row & 7);
    glds16(Agm + (size_t)(row0 + row) * 256 + cs * 8, &Bs[idx * 8]);
  }
  __syncthreads();

  s16x8 afr[2][8];
#pragma unroll
  for (int mi = 0; mi < 2; ++mi) {
    int row = wy + mi * 16 + l16;
#pragma unroll
    for (int ki = 0; ki < 8; ++ki) {
      int cl = (ki * 4 + quad) ^ (row & 7);
      afr[mi][ki] = *(const s16x8*)&Bs[row * 256 + cl * 8];
    }
  }
  __syncthreads();

  f32x4 outacc[2][2];
#pragma unroll
  for (int a = 0; a < 2; ++a)
#pragma unroll
    for (int b = 0; b < 2; ++b) outacc[a][b] = (f32x4){0.f, 0.f, 0.f, 0.f};

  for (int tl = dh * 8; tl < dh * 8 + 8; ++tl) {
    const int brow0 = tl * 64;
#pragma unroll
    for (int p = 0; p < 8; ++p) {
      int idx = p * 256 + t; int row = idx >> 5; int cs = (idx & 31) ^ (row & 7);
      glds16(A.Bt + (size_t)(brow0 + row) * 256 + cs * 8, &Bs[idx * 8]);
    }
    __syncthreads();

    f32x4 acc[2][2];
#pragma unroll
    for (int a = 0; a < 2; ++a)
#pragma unroll
      for (int b = 0; b < 2; ++b) acc[a][b] = (f32x4){0.f, 0.f, 0.f, 0.f};

#pragma unroll
    for (int ki = 0; ki < 8; ++ki) {
      s16x8 bfr[2];
#pragma unroll
      for (int ni = 0; ni < 2; ++ni) {
        int row = wx + ni * 16 + l16;
        int cl = (ki * 4 + quad) ^ (row & 7);
        bfr[ni] = *(const s16x8*)&Bs[row * 256 + cl * 8];
      }
#pragma unroll
      for (int mi = 0; mi < 2; ++mi)
#pragma unroll
        for (int ni = 0; ni < 2; ++ni)
          acc[mi][ni] = __builtin_amdgcn_mfma_f32_16x16x32_bf16(afr[mi][ki], bfr[ni], acc[mi][ni], 0, 0, 0);
    }

#pragma unroll
    for (int mi = 0; mi < 2; ++mi) {
      int nl = (wy + mi * 16 + quad * 4) >> 3;
      float s = ewS[nl][tl];
#pragma unroll
      for (int ni = 0; ni < 2; ++ni)
#pragma unroll
        for (int r = 0; r < 4; ++r)
          outacc[mi][ni][r] += s * acc[mi][ni][r];
    }
    __syncthreads();
  }

  // write raw partials: Pacc[((dh*3+mode)*8000 + row)*64 + o]
#pragma unroll
  for (int mi = 0; mi < 2; ++mi)
#pragma unroll
    for (int ni = 0; ni < 2; ++ni)
#pragma unroll
      for (int r = 0; r < 4; ++r) {
        int row = row0 + wy + mi * 16 + quad * 4 + r;
        int o = wx + ni * 16 + l16;
        Pacc[((size_t)(dh * 3 + mode) * 8000 + row) * 64 + o] = outacc[mi][ni][r];
      }
}

// ---------------------------------------------------------------------------
// epi_u: out = r*state + (1-r)*tanh(p0+p1+BiU). 3*8000*64 = 1.536M threads.
// ---------------------------------------------------------------------------
__global__ void epi_u(const float* __restrict__ Pacc, const float* __restrict__ BiU,
                      const float* __restrict__ Rb,
                      const float* __restrict__ st0, const float* __restrict__ st1,
                      const float* __restrict__ st2, float* __restrict__ out) {
  int idx = blockIdx.x * blockDim.x + threadIdx.x;
  if (idx >= 1536000) return;
  int mode = idx / 512000, rem = idx % 512000;
  int row = rem >> 6, o = rem & 63;
  int n = row >> 3, b = row & 7;
  float pre = Pacc[((size_t)mode * 8000 + row) * 64 + o] +
              Pacc[((size_t)(3 + mode) * 8000 + row) * 64 + o] +
              BiU[(size_t)mode * 64000 + n * 64 + o];
  float hc = tanhf(pre);
  float rr = Rb[(size_t)mode * 512000 + row * 64 + o];
  const float* st = (mode == 0) ? st0 : (mode == 1) ? st1 : st2;
  out[(size_t)mode * 512000 + (b * 1000 + n) * 64 + o] =
      rr * st[(b * 1000 + n) * 64 + o] + (1.f - rr) * hc;
}

// ---------------------------------------------------------------------------
extern "C" void kernel_launch(void* const* d_in, const int* in_sizes, int n_in,
                              void* d_out, int out_size, void* d_ws, size_t ws_size,
                              hipStream_t stream) {
  const float* x[3]   = {(const float*)d_in[0], (const float*)d_in[1], (const float*)d_in[2]};
  const float* st[3]  = {(const float*)d_in[3], (const float*)d_in[4], (const float*)d_in[5]};
  const float* S[3]   = {(const float*)d_in[6], (const float*)d_in[7], (const float*)d_in[8]};
  const float* emb[3] = {(const float*)d_in[9], (const float*)d_in[10], (const float*)d_in[11]};
  const float* me = (const float*)d_in[12];
  const float* Wg = (const float*)d_in[13];
  const float* Bg = (const float*)d_in[14];
  const float* Wu = (const float*)d_in[15];
  const float* Bu = (const float*)d_in[16];
  float* out = (float*)d_out;

  float* BiG = (float*)d_ws;            // 3*1000*128
  float* BiU = BiG + 384000;            // 3*1000*64
  float* Rb  = BiU + 192000;            // 3*8000*64
  u16* S16 = (u16*)(Rb + 1536000);      // 3*1024*1024
  u16* Xt  = S16 + 3145728;             // 3*640*1024
  u16* T1t = Xt + 1966080;              // 3*640*1024
  u16* ZSt = T1t + 1966080;             // 3*512*1024
  u16* SZ1t= ZSt + 1572864;             // 3*512*1024
  u16* Ag  = SZ1t + 1572864;            // 3*8000*256
  u16* AgU = Ag + 6144000;              // 3*8000*256
  u16* BtG = AgU + 6144000;             // 2048*256
  u16* BtU = BtG + 524288;              // 1024*256
  float* PaccU = (float*)Ag;            // overlay: [2][3][8000][64] f32

  {
    PrepAuxArgs P;
    for (int m = 0; m < 3; ++m) { P.x[m] = x[m]; P.st[m] = st[m]; P.S[m] = S[m]; }
    P.S16 = S16; P.Xt = Xt; P.Ag = Ag; P.AgU = AgU; P.T1t = T1t; P.ZSt = ZSt; P.SZ1t = SZ1t;
    P.e0 = emb[0]; P.e1 = emb[1]; P.e2 = emb[2]; P.me = me;
    P.Bg = Bg; P.Bu = Bu; P.Wg = Wg; P.Wu = Wu;
    P.BiG = BiG; P.BiU = BiU; P.BtG = BtG; P.BtU = BtU;
    prep_aux<<<13431, 256, 0, stream>>>(P);
  }

  // cheb1: T1t = Xt @ S^T -> T1t + Ag[80..159] (+AgU x-part)
  {
    ChebArgs2 a;
    for (int m = 0; m < 3; ++m) {
      a.S16[m] = S16 + (size_t)m * 1048576; a.A[m] = Xt + (size_t)m * 655360;
      a.Res[m] = nullptr; a.Yt[m] = T1t + (size_t)m * 655360;
      a.AgA[m] = Ag + (size_t)m * 2048000; a.AgX[m] = AgU + (size_t)m * 2048000;
    }
    cheb_v6<<<dim3(16, 20, 3), 256, 0, stream>>>(a, 80, 80, 1.f, 0.f, 2 | 4);
  }
  // cheb2: T2t = 2*T1t @ S^T - Xt -> Ag[160..239] (+AgU x-part)
  {
    ChebArgs2 a;
    for (int m = 0; m < 3; ++m) {
      a.S16[m] = S16 + (size_t)m * 1048576; a.A[m] = T1t + (size_t)m * 655360;
      a.Res[m] = Xt + (size_t)m * 655360; a.Yt[m] = nullptr;
      a.AgA[m] = Ag + (size_t)m * 2048000; a.AgX[m] = AgU + (size_t)m * 2048000;
    }
    cheb_v6<<<dim3(16, 20, 3), 256, 0, stream>>>(a, 80, 160, 2.f, -1.f, 1 | 4);
  }
  // gate meta (128-row blocks, fixed launch bounds)
  {
    Meta3Args a;
    a.Ag = Ag; a.Bt = BtG; a.me = me; a.Bias = BiG;
    a.ZSt = ZSt; a.AgU = AgU; a.Rb = Rb; a.out = out;
    for (int m = 0; m < 3; ++m) { a.emb[m] = emb[m]; a.state[m] = st[m]; }
    meta3g<<<dim3(2, 63, 3), 512, 0, stream>>>(a, 128);
  }
  // cheb3: SZ1t = ZSt @ S^T -> SZ1t + AgU[96..159]
  {
    ChebArgs2 a;
    for (int m = 0; m < 3; ++m) {
      a.S16[m] = S16 + (size_t)m * 1048576; a.A[m] = ZSt + (size_t)m * 524288;
      a.Res[m] = nullptr; a.Yt[m] = SZ1t + (size_t)m * 524288;
      a.AgA[m] = AgU + (size_t)m * 2048000; a.AgX[m] = nullptr;
    }
    cheb_v6<<<dim3(16, 16, 3), 256, 0, stream>>>(a, 64, 96, 1.f, 0.f, 2);
  }
  // cheb4: SZ2t = 2*SZ1t @ S^T - ZSt -> AgU[176..239]
  {
    ChebArgs2 a;
    for (int m = 0; m < 3; ++m) {
      a.S16[m] = S16 + (size_t)m * 1048576; a.A[m] = SZ1t + (size_t)m * 524288;
      a.Res[m] = ZSt + (size_t)m * 524288; a.Yt[m] = nullptr;
      a.AgA[m] = AgU + (size_t)m * 2048000; a.AgX[m] = nullptr;
    }
    cheb_v6<<<dim3(16, 16, 3), 256, 0, stream>>>(a, 64, 176, 2.f, -1.f, 1);
  }
  // update meta (split-d): reads AgU; writes PaccU partials (Ag overlay)
  {
    Meta3Args a;
    a.Ag = AgU; a.Bt = BtU; a.me = me; a.Bias = BiU;
    a.ZSt = ZSt; a.AgU = AgU; a.Rb = Rb; a.out = out;
    for (int m = 0; m < 3; ++m) { a.emb[m] = emb[m]; a.state[m] = st[m]; }
    meta3u<<<dim3(2, 125, 3), 256, 0, stream>>>(a, PaccU);
  }
  // update epilogue: out = r*state + (1-r)*tanh(p0+p1+BiU)
  epi_u<<<6000, 256, 0, stream>>>(PaccU, BiU, Rb, st[0], st[1], st[2], out);
}